// Round 10
// baseline (288.205 us; speedup 1.0000x reference)
//
#include <hip/hip_runtime.h>
#include <hip/hip_fp16.h>
#include <cmath>

#define NROWS  65536
#define DIM    512
#define KCODES 2048
#define NDTOT  33554432LL   // NROWS*DIM
// refine trigger: f16-product error (14*sigma = 0.0625) + key truncation (<=0.5)
#define MARGIN_P 0.5625f

typedef __attribute__((ext_vector_type(8))) _Float16 f16x8;  // 8 f16 = 1 MFMA operand
typedef __attribute__((ext_vector_type(4))) float f32x4;

// branchless sorted-top3 insert of packed key v (u32 min/max keep regs, no addresses)
#define KINS3(K1,K2,K3,V) do {                       \
    unsigned int _v = (V);                           \
    unsigned int _h1 = max((K1), _v); (K1) = min((K1), _v); \
    unsigned int _h2 = max((K2), _h1); (K2) = min((K2), _h1); \
    (K3) = min((K3), _h2);                           \
} while (0)

// in-place merge of two sorted triples (A <- merge(A,B)), packed-key order
#define MRG3(A1,A2,A3,B1,B2,B3) do {                               \
    unsigned int _x1 = min((A1),(B1)), _y1 = max((A1),(B1));       \
    unsigned int _x2 = min((A2),(B2)), _y2 = max((A2),(B2));       \
    unsigned int _x3 = min((A3),(B3));                             \
    (A1) = _x1; (A2) = min(_y1,_x2);                               \
    (A3) = min(max(_y1,_x2), min(_x3,_y2));                        \
} while (0)

__device__ inline void gll16(const void* g, void* l) {
    __builtin_amdgcn_global_load_lds(
        (const __attribute__((address_space(1))) void*)g,
        (__attribute__((address_space(3))) void*)l, 16, 0, 0);
}

// ---------------- kernel 1a: x -> f16 fragment-order + row norms ----------------
// per 128-row slab rb: [ks64 8][ksub 2][frow 8][lane 64][16B];
// lane = ((k%32)/8)*16 + row%16, frow = (row%128)/16.
__global__ __launch_bounds__(256) void k_prep(const float* __restrict__ src,
                                              char* __restrict__ dst,
                                              float* __restrict__ norms) {
    long gid = (long)blockIdx.x * 256 + threadIdx.x;
    int row = (int)(gid >> 6);
    int k8  = (int)(gid & 63);           // chunk of 8 dims
    const float4* s = (const float4*)(src + (size_t)row * DIM + k8 * 8);
    float4 v0 = s[0], v1 = s[1];
    float vv[8] = {v0.x, v0.y, v0.z, v0.w, v1.x, v1.y, v1.z, v1.w};
    unsigned int hw[4];
    float nrm = 0.f;
    #pragma unroll
    for (int j = 0; j < 4; ++j) {
        unsigned int h0 = __half_as_ushort(__float2half_rn(vv[2*j]));
        unsigned int h1 = __half_as_ushort(__float2half_rn(vv[2*j+1]));
        hw[j] = h0 | (h1 << 16);
        nrm = fmaf(vv[2*j], vv[2*j], nrm);
        nrm = fmaf(vv[2*j+1], vv[2*j+1], nrm);
    }
    int rb = row >> 7, frow = (row >> 4) & 7;
    int k32 = k8 >> 2, sub = k8 & 3;
    int ksub = k32 & 1, ks64 = k32 >> 1;
    int l = sub * 16 + (row & 15);
    size_t off = (size_t)(rb * 8 + ks64) * 16384 + (size_t)ksub * 8192
               + (size_t)frow * 1024 + (size_t)l * 16;
    *(uint4*)(dst + off) = make_uint4(hw[0], hw[1], hw[2], hw[3]);
    #pragma unroll
    for (int o = 32; o; o >>= 1) nrm += __shfl_xor(nrm, o, 64);
    if ((threadIdx.x & 63) == 0) norms[row] = nrm;
}

// ---------------- kernel 1b: w -> f16 B-tile order + norms ----------------
// tile (cb 8 of 256 cols, ks32 16): 16384 B = [fcol 16][lane 64][16B];
// lane = ((k%32)/8)*16 + col%16, fcol = (col%256)/16.
__global__ __launch_bounds__(256) void k_prepw(const float* __restrict__ src,
                                               char* __restrict__ dst,
                                               float* __restrict__ norms) {
    long gid = (long)blockIdx.x * 256 + threadIdx.x;
    int c  = (int)(gid >> 6);
    int k8 = (int)(gid & 63);
    const float4* s = (const float4*)(src + (size_t)c * DIM + k8 * 8);
    float4 v0 = s[0], v1 = s[1];
    float vv[8] = {v0.x, v0.y, v0.z, v0.w, v1.x, v1.y, v1.z, v1.w};
    unsigned int hw[4];
    float nrm = 0.f;
    #pragma unroll
    for (int j = 0; j < 4; ++j) {
        unsigned int h0 = __half_as_ushort(__float2half_rn(vv[2*j]));
        unsigned int h1 = __half_as_ushort(__float2half_rn(vv[2*j+1]));
        hw[j] = h0 | (h1 << 16);
        nrm = fmaf(vv[2*j], vv[2*j], nrm);
        nrm = fmaf(vv[2*j+1], vv[2*j+1], nrm);
    }
    int cb = c >> 8, fcol = (c >> 4) & 15;
    int ks32 = k8 >> 2, sub = k8 & 3;
    int l = sub * 16 + (c & 15);
    size_t off = (size_t)((cb * 16 + ks32) * 16 + fcol) * 1024 + (size_t)l * 16;
    *(uint4*)(dst + off) = make_uint4(hw[0], hw[1], hw[2], hw[3]);
    #pragma unroll
    for (int o = 32; o; o >>= 1) nrm += __shfl_xor(nrm, o, 64);
    if ((threadIdx.x & 63) == 0) norms[c] = nrm;
}

// ---------------- kernel 2: f16 MFMA GEMM, A LDS-resident, 1-barrier pipeline ----------
// 512 blocks x 512 threads (8 waves 2x4, 1 block/CU at 160KB LDS).
// smem: A slab 128KB (staged once) + B dbuf 2x16KB. Block tile 128x256,
// wave tile 64x64 (acc[4][4]). Per step: {barrier; stage B(t+1); setprio(1);
// MFMA; setprio(0); vmcnt(0) drain hidden behind compute}. ONE barrier/step:
// stage(t+1)->p^1 is safe after barrier(t) (all waves done with compute(t-1),
// the last reader of p^1); vmcnt(0)-before-barrier guarantees every wave's
// stage chunks landed before any wave computes from them.
__global__ __launch_bounds__(512, 1) void k_gemm(const char* __restrict__ xp,
                                                 const char* __restrict__ wp,
                                                 const float* __restrict__ wnorm,
                                                 int* __restrict__ idxo,
                                                 int* __restrict__ cand2o,
                                                 int* __restrict__ cand3o,
                                                 float* __restrict__ bestd) {
    __shared__ char smem[163840];   // A @0 (131072) ; Bs[2] @131072,147456
    const int tid = threadIdx.x;
    const int lane = tid & 63;
    const int wid = tid >> 6;                // 0..7
    const int wr = wid >> 2, wc = wid & 3;   // wave grid 2 x 4
    const int rb = blockIdx.x;
    const char* xsrc = xp + (size_t)rb * 131072;

    f32x4 acc[4][4];
    #pragma unroll
    for (int i = 0; i < 4; ++i)
        #pragma unroll
        for (int j = 0; j < 4; ++j) acc[i][j] = (f32x4){0.f, 0.f, 0.f, 0.f};

    unsigned int k1[16], k2[16], k3[16];
    #pragma unroll
    for (int s = 0; s < 16; ++s) { k1[s] = k2[s] = k3[s] = 0xFFFFFFFFu; }

    // prologue: whole A slab (once) + B tile 0; drain before first barrier
    #pragma unroll
    for (int i = 0; i < 16; ++i) {
        int c = wid * 16 + i;                // 128 chunks of 1024B
        gll16(xsrc + c * 1024 + lane * 16, smem + c * 1024);
    }
    gll16(wp + (wid * 2 + 0) * 1024 + lane * 16, smem + 131072 + (wid * 2 + 0) * 1024);
    gll16(wp + (wid * 2 + 1) * 1024 + lane * 16, smem + 131072 + (wid * 2 + 1) * 1024);
    asm volatile("s_waitcnt vmcnt(0)" ::: "memory");

    #pragma unroll 2
    for (int t = 0; t < 128; ++t) {
        __builtin_amdgcn_s_barrier();        // B(t) landed everywhere; p^1 readers done
        int p = t & 1;
        if (t < 127) {                       // prefetch B(t+1); lands during compute
            const char* bsrc = wp + (size_t)(t + 1) * 16384;
            char* bdst = smem + 131072 + (p ^ 1) * 16384;
            gll16(bsrc + (wid * 2 + 0) * 1024 + lane * 16, bdst + (wid * 2 + 0) * 1024);
            gll16(bsrc + (wid * 2 + 1) * 1024 + lane * 16, bdst + (wid * 2 + 1) * 1024);
        }

        int ks32 = t & 15;
        const char* A = smem + (ks32 >> 1) * 16384 + (ks32 & 1) * 8192;
        const char* B = smem + 131072 + p * 16384;
        f16x8 ah[4];
        #pragma unroll
        for (int fr = 0; fr < 4; ++fr)
            ah[fr] = *(const f16x8*)(A + (wr * 4 + fr) * 1024 + lane * 16);
        __builtin_amdgcn_s_setprio(1);
        #pragma unroll
        for (int fc = 0; fc < 4; ++fc) {
            f16x8 bh = *(const f16x8*)(B + (wc * 4 + fc) * 1024 + lane * 16);
            #pragma unroll
            for (int fr = 0; fr < 4; ++fr)
                acc[fr][fc] = __builtin_amdgcn_mfma_f32_16x16x32_f16(ah[fr], bh, acc[fr][fc], 0, 0, 0);
        }
        __builtin_amdgcn_s_setprio(0);

        if (ks32 == 15) {                    // full K done for this cb: top-3 update
            int cb = t >> 4;
            #pragma unroll
            for (int fc = 0; fc < 4; ++fc) {
                unsigned int col = (unsigned)(cb * 256 + wc * 64 + fc * 16 + (lane & 15));
                float wnb = wnorm[col] + 1024.f;   // bias keeps key positive, exp band 2^10
                #pragma unroll
                for (int fr = 0; fr < 4; ++fr) {
                    #pragma unroll
                    for (int reg = 0; reg < 4; ++reg) {
                        float kd = fmaf(-2.f, acc[fr][fc][reg], wnb);
                        unsigned int key = (__float_as_uint(kd) & 0xFFFFF800u) | col;
                        int s = fr * 4 + reg;
                        KINS3(k1[s], k2[s], k3[s], key);
                    }
                    acc[fr][fc] = (f32x4){0.f, 0.f, 0.f, 0.f};
                }
            }
        }
        // own stage(t+1) chunks landed (hidden behind ~600cy compute);
        // next barrier then makes them visible to all waves
        asm volatile("s_waitcnt vmcnt(0)" ::: "memory");
    }

    // butterfly top-3 merge across the 16 column-lanes of each slot
    #pragma unroll
    for (int s = 0; s < 16; ++s) {
        #pragma unroll
        for (int off = 1; off < 16; off <<= 1) {
            unsigned int b1 = (unsigned)__shfl_xor((int)k1[s], off, 16);
            unsigned int b2 = (unsigned)__shfl_xor((int)k2[s], off, 16);
            unsigned int b3 = (unsigned)__shfl_xor((int)k3[s], off, 16);
            MRG3(k1[s], k2[s], k3[s], b1, b2, b3);
        }
    }
    // lane (lane&15)==s owns slot s; static-unrolled select (rule #20)
    unsigned int m1 = 0, m2 = 0, m3 = 0;
    #pragma unroll
    for (int s = 0; s < 16; ++s) {
        bool mine = (lane & 15) == s;
        m1 = mine ? k1[s] : m1;
        m2 = mine ? k2[s] : m2;
        m3 = mine ? k3[s] : m3;
    }
    int sl = lane & 15;
    int rowl = wr * 64 + (sl >> 2) * 16 + (lane >> 4) * 4 + (sl & 3);
    __syncthreads();                         // MFMA loop fully done; reuse A region
    ((uint4*)smem)[rowl * 4 + wc] = make_uint4(m1, m2, m3, 0u);
    __syncthreads();
    if (tid < 128) {
        uint4 a = ((const uint4*)smem)[tid * 4 + 0];
        uint4 b = ((const uint4*)smem)[tid * 4 + 1];
        uint4 c = ((const uint4*)smem)[tid * 4 + 2];
        uint4 d = ((const uint4*)smem)[tid * 4 + 3];
        unsigned int K1 = a.x, K2 = a.y, K3 = a.z;
        MRG3(K1, K2, K3, b.x, b.y, b.z);
        MRG3(K1, K2, K3, c.x, c.y, c.z);
        MRG3(K1, K2, K3, d.x, d.y, d.z);
        float f1 = __uint_as_float(K1 & 0xFFFFF800u) - 1024.f;
        float f2 = __uint_as_float(K2 & 0xFFFFF800u) - 1024.f;
        float f3 = __uint_as_float(K3 & 0xFFFFF800u) - 1024.f;
        int row = rb * 128 + tid;
        idxo[row]   = (int)(K1 & 0x7FFu);
        bestd[row]  = f1;
        cand2o[row] = (f2 - f1 < MARGIN_P) ? (int)(K2 & 0x7FFu) : -1;
        cand3o[row] = (f3 - f1 < MARGIN_P) ? (int)(K3 & 0x7FFu) : -1;
    }
}

// ---------------- kernel 3: fused fp64 refine + gather + loss partial + histogram ----
__global__ __launch_bounds__(256) void k_gather2(const float* __restrict__ x,
                                                 const float* __restrict__ w,
                                                 const int* __restrict__ idxo,
                                                 const int* __restrict__ cand2o,
                                                 const int* __restrict__ cand3o,
                                                 const float* __restrict__ bestd,
                                                 const float* __restrict__ xnorm,
                                                 float* __restrict__ out,
                                                 int* __restrict__ hist,
                                                 double* __restrict__ part) {
    __shared__ double red[4];
    int wid = threadIdx.x >> 6, lane = threadIdx.x & 63;
    int n = blockIdx.x * 4 + wid;
    int c1 = idxo[n];
    int c2 = cand2o[n];
    int cfin = c1;
    double dist = (double)bestd[n];
    if (c2 >= 0) {
        int c3 = cand3o[n];
        int c3e = (c3 < 0) ? c1 : c3;
        const float* xr = x + (size_t)n * DIM;
        const float* w1 = w + (size_t)c1 * DIM;
        const float* w2 = w + (size_t)c2 * DIM;
        const float* w3 = w + (size_t)c3e * DIM;
        double s1 = 0.0, s2 = 0.0, s3 = 0.0;
        #pragma unroll
        for (int j = 0; j < DIM / 64; ++j) {
            int d = lane + 64 * j;
            double xv = (double)xr[d];
            double a = (double)w1[d], b = (double)w2[d], c = (double)w3[d];
            s1 += a * a - 2.0 * xv * a;
            s2 += b * b - 2.0 * xv * b;
            s3 += c * c - 2.0 * xv * c;
        }
        #pragma unroll
        for (int off = 32; off; off >>= 1) {
            s1 += __shfl_xor(s1, off, 64);
            s2 += __shfl_xor(s2, off, 64);
            s3 += __shfl_xor(s3, off, 64);
        }
        double bs = s1; int bi = c1;
        if (s2 < bs || (s2 == bs && c2 < bi)) { bs = s2; bi = c2; }
        if (c3 >= 0 && (s3 < bs || (s3 == bs && c3 < bi))) { bs = s3; bi = c3; }
        cfin = bi;
        dist = bs;
    }
    const float* wq = w + (size_t)cfin * DIM;
    float* oq = out + 1 + (size_t)n * DIM;   // quantized_st == quantized numerically
    #pragma unroll
    for (int j = 0; j < DIM / 64; ++j) {
        int d = j * 64 + lane;
        oq[d] = wq[d];
    }
    if (lane == 0) {
        red[wid] = dist + (double)xnorm[n];  // ||x-w||^2 = (||w||^2-2xw) + ||x||^2
        atomicAdd(&hist[cfin], 1);
        out[2 + NDTOT + n] = (float)cfin;
    }
    __syncthreads();
    if (threadIdx.x == 0)
        part[blockIdx.x] = red[0] + red[1] + red[2] + red[3];
}

// ---------------- kernel 4: deterministic finalize (loss + perplexity) ----------------
__global__ __launch_bounds__(256) void k_final2(const double* __restrict__ part,
                                                const int* __restrict__ hist,
                                                float* __restrict__ out) {
    __shared__ double sm[256];
    int t = threadIdx.x;
    double s = 0.0;
    for (int i = t; i < NROWS / 4; i += 256) s += part[i];
    sm[t] = s; __syncthreads();
    for (int off = 128; off; off >>= 1) { if (t < off) sm[t] += sm[t + off]; __syncthreads(); }
    if (t == 0) out[0] = (float)(sm[0] * 0.25 / (double)NDTOT);
    __syncthreads();
    double e = 0.0;
    for (int k = t; k < KCODES; k += 256) {
        double p = (double)hist[k] / (double)NROWS;
        e -= p * log(p + 1e-10);
    }
    sm[t] = e; __syncthreads();
    for (int off = 128; off; off >>= 1) { if (t < off) sm[t] += sm[t + off]; __syncthreads(); }
    if (t == 0) out[1 + NDTOT] = (float)exp(sm[0]);
}

extern "C" void kernel_launch(void* const* d_in, const int* in_sizes, int n_in,
                              void* d_out, int out_size, void* d_ws, size_t ws_size,
                              hipStream_t stream) {
    const float* x = (const float*)d_in[0];   // [64,1024,512] fp32
    const float* w = (const float*)d_in[1];   // [2048,512] fp32
    float* out = (float*)d_out;
    char* ws = (char*)d_ws;

    // xp (64 MB f16 fragment-ordered) lives in the d_out quantized region:
    // k_gemm consumes it before k_gather2 overwrites every byte with outputs.
    char* xp = (char*)d_out + 16;

    char*   wp    = ws;                            // 2 MB
    float*  wnorm = (float*)(ws + 2097152);        // 8 KB
    int*    idxo  = (int*)(ws + 2105344);          // 256 KB
    int*    cand2 = (int*)(ws + 2367488);          // 256 KB
    int*    cand3 = (int*)(ws + 2629632);          // 256 KB
    int*    hist  = (int*)(ws + 2891776);          // 8 KB
    float*  xnorm = (float*)(ws + 2899968);        // 256 KB
    float*  bestd = (float*)(ws + 3162112);        // 256 KB
    double* part  = (double*)(ws + 3424256);       // 128 KB

    hipMemsetAsync(hist, 0, KCODES * sizeof(int), stream);
    k_prepw  <<<(KCODES * 64) / 256, 256, 0, stream>>>(w, wp, wnorm);
    k_prep   <<<(NROWS * 64) / 256, 256, 0, stream>>>(x, xp, xnorm);
    k_gemm   <<<NROWS / 128, 512, 0, stream>>>(xp, wp, wnorm, idxo, cand2, cand3, bestd);
    k_gather2<<<NROWS / 4, 256, 0, stream>>>(x, w, idxo, cand2, cand3, bestd, xnorm, out, hist, part);
    k_final2 <<<1, 256, 0, stream>>>(part, hist, out);
}

// Round 11
// 285.256 us; speedup vs baseline: 1.0103x; 1.0103x over previous
//
#include <hip/hip_runtime.h>
#include <hip/hip_fp16.h>
#include <cmath>

#define NROWS  65536
#define DIM    512
#define KCODES 2048
#define NDTOT  33554432LL   // NROWS*DIM
// refine trigger: f16-product error (14*sigma = 0.0625) + key truncation (0.001)
#define MARGIN_P 0.0635f

typedef __attribute__((ext_vector_type(8))) _Float16 f16x8;  // 8 f16 = 1 MFMA operand
typedef __attribute__((ext_vector_type(4))) float f32x4;

// branchless sorted-top3 insert of packed key v (u32 min/max keep regs, no addresses)
#define KINS3(K1,K2,K3,V) do {                       \
    unsigned int _v = (V);                           \
    unsigned int _h1 = max((K1), _v); (K1) = min((K1), _v); \
    unsigned int _h2 = max((K2), _h1); (K2) = min((K2), _h1); \
    (K3) = min((K3), _h2);                           \
} while (0)

// in-place merge of two sorted triples (A <- merge(A,B)), packed-key order
#define MRG3(A1,A2,A3,B1,B2,B3) do {                               \
    unsigned int _x1 = min((A1),(B1)), _y1 = max((A1),(B1));       \
    unsigned int _x2 = min((A2),(B2)), _y2 = max((A2),(B2));       \
    unsigned int _x3 = min((A3),(B3));                             \
    (A1) = _x1; (A2) = min(_y1,_x2);                               \
    (A3) = min(max(_y1,_x2), min(_x3,_y2));                        \
} while (0)

// key pack: dist+1024 in [1024,2048) -> exponent constant -> keep mantissa[22:2]
// in key[31:11], col in key[10:0]. umin order == (dist, col) lex order.
#define FDEC(K) (__uint_as_float(0x44800000u | ((((K) >> 11) & 0x1FFFFFu) << 2)) - 1024.f)

__device__ inline void gll16(const void* g, void* l) {
    __builtin_amdgcn_global_load_lds(
        (const __attribute__((address_space(1))) void*)g,
        (__attribute__((address_space(3))) void*)l, 16, 0, 0);
}

// ---------------- kernel 1a: x -> f16 fragment-order + row norms ----------------
// per 128-row slab rb: [ks64 8][ksub 2][frow 8][lane 64][16B];
// lane = ((k%32)/8)*16 + row%16, frow = (row%128)/16.
__global__ __launch_bounds__(256) void k_prep(const float* __restrict__ src,
                                              char* __restrict__ dst,
                                              float* __restrict__ norms) {
    long gid = (long)blockIdx.x * 256 + threadIdx.x;
    int row = (int)(gid >> 6);
    int k8  = (int)(gid & 63);           // chunk of 8 dims
    const float4* s = (const float4*)(src + (size_t)row * DIM + k8 * 8);
    float4 v0 = s[0], v1 = s[1];
    float vv[8] = {v0.x, v0.y, v0.z, v0.w, v1.x, v1.y, v1.z, v1.w};
    unsigned int hw[4];
    float nrm = 0.f;
    #pragma unroll
    for (int j = 0; j < 4; ++j) {
        unsigned int h0 = __half_as_ushort(__float2half_rn(vv[2*j]));
        unsigned int h1 = __half_as_ushort(__float2half_rn(vv[2*j+1]));
        hw[j] = h0 | (h1 << 16);
        nrm = fmaf(vv[2*j], vv[2*j], nrm);
        nrm = fmaf(vv[2*j+1], vv[2*j+1], nrm);
    }
    int rb = row >> 7, frow = (row >> 4) & 7;
    int k32 = k8 >> 2, sub = k8 & 3;
    int ksub = k32 & 1, ks64 = k32 >> 1;
    int l = sub * 16 + (row & 15);
    size_t off = (size_t)(rb * 8 + ks64) * 16384 + (size_t)ksub * 8192
               + (size_t)frow * 1024 + (size_t)l * 16;
    *(uint4*)(dst + off) = make_uint4(hw[0], hw[1], hw[2], hw[3]);
    #pragma unroll
    for (int o = 32; o; o >>= 1) nrm += __shfl_xor(nrm, o, 64);
    if ((threadIdx.x & 63) == 0) norms[row] = nrm;
}

// ---------------- kernel 1b: w -> f16 B-tile order + norms ----------------
// tile (cb 8 of 256 cols, ks32 16): 16384 B = [fcol 16][lane 64][16B];
// lane = ((k%32)/8)*16 + col%16, fcol = (col%256)/16.
__global__ __launch_bounds__(256) void k_prepw(const float* __restrict__ src,
                                               char* __restrict__ dst,
                                               float* __restrict__ norms) {
    long gid = (long)blockIdx.x * 256 + threadIdx.x;
    int c  = (int)(gid >> 6);
    int k8 = (int)(gid & 63);
    const float4* s = (const float4*)(src + (size_t)c * DIM + k8 * 8);
    float4 v0 = s[0], v1 = s[1];
    float vv[8] = {v0.x, v0.y, v0.z, v0.w, v1.x, v1.y, v1.z, v1.w};
    unsigned int hw[4];
    float nrm = 0.f;
    #pragma unroll
    for (int j = 0; j < 4; ++j) {
        unsigned int h0 = __half_as_ushort(__float2half_rn(vv[2*j]));
        unsigned int h1 = __half_as_ushort(__float2half_rn(vv[2*j+1]));
        hw[j] = h0 | (h1 << 16);
        nrm = fmaf(vv[2*j], vv[2*j], nrm);
        nrm = fmaf(vv[2*j+1], vv[2*j+1], nrm);
    }
    int cb = c >> 8, fcol = (c >> 4) & 15;
    int ks32 = k8 >> 2, sub = k8 & 3;
    int l = sub * 16 + (c & 15);
    size_t off = (size_t)((cb * 16 + ks32) * 16 + fcol) * 1024 + (size_t)l * 16;
    *(uint4*)(dst + off) = make_uint4(hw[0], hw[1], hw[2], hw[3]);
    #pragma unroll
    for (int o = 32; o; o >>= 1) nrm += __shfl_xor(nrm, o, 64);
    if ((threadIdx.x & 63) == 0) norms[c] = nrm;
}

// top-3 epilogue per 256-col block CB (acc consumed + reset)
#define EPI(CB) do {                                                         \
    _Pragma("unroll") for (int fc = 0; fc < 4; ++fc) {                       \
        unsigned int col = (unsigned)((CB) * 256 + wc * 64 + fc * 16 + (lane & 15)); \
        float wnb = wnorm[col] + 1024.f;                                     \
        _Pragma("unroll") for (int fr = 0; fr < 4; ++fr) {                   \
            _Pragma("unroll") for (int reg = 0; reg < 4; ++reg) {            \
                float kd = fmaf(-2.f, acc[fr][fc][reg], wnb);                \
                unsigned int key = ((__float_as_uint(kd) << 9) & 0xFFFFF800u) | col; \
                int s = fr * 4 + reg;                                        \
                KINS3(k1[s], k2[s], k3[s], key);                             \
            }                                                                \
            acc[fr][fc] = (f32x4){0.f, 0.f, 0.f, 0.f};                       \
        }                                                                    \
    }                                                                        \
} while (0)

// one barrier-free step: prefetch B(T+1) global->NXT regs, ds_read A, 16 MFMA
// with CUR regs, top-3 epilogue at the end of each 256-col block.
#define GSTEP(T, CUR0, CUR1, CUR2, CUR3, NXT0, NXT1, NXT2, NXT3) do {        \
    {                                                                        \
        const char* _n = wp + ((size_t)((T) + 1) << 14) + (size_t)(wc * 4) * 1024 + (size_t)lane * 16; \
        NXT0 = *(const f16x8*)(_n);                                          \
        NXT1 = *(const f16x8*)(_n + 1024);                                   \
        NXT2 = *(const f16x8*)(_n + 2048);                                   \
        NXT3 = *(const f16x8*)(_n + 3072);                                   \
    }                                                                        \
    {                                                                        \
        int _ks = (T) & 15;                                                  \
        const char* _a = smem + (_ks >> 1) * 16384 + (_ks & 1) * 8192        \
                       + (wr * 4) * 1024 + lane * 16;                        \
        f16x8 _a0 = *(const f16x8*)(_a);                                     \
        f16x8 _a1 = *(const f16x8*)(_a + 1024);                              \
        f16x8 _a2 = *(const f16x8*)(_a + 2048);                              \
        f16x8 _a3 = *(const f16x8*)(_a + 3072);                              \
        acc[0][0] = __builtin_amdgcn_mfma_f32_16x16x32_f16(_a0, CUR0, acc[0][0], 0, 0, 0); \
        acc[1][0] = __builtin_amdgcn_mfma_f32_16x16x32_f16(_a1, CUR0, acc[1][0], 0, 0, 0); \
        acc[2][0] = __builtin_amdgcn_mfma_f32_16x16x32_f16(_a2, CUR0, acc[2][0], 0, 0, 0); \
        acc[3][0] = __builtin_amdgcn_mfma_f32_16x16x32_f16(_a3, CUR0, acc[3][0], 0, 0, 0); \
        acc[0][1] = __builtin_amdgcn_mfma_f32_16x16x32_f16(_a0, CUR1, acc[0][1], 0, 0, 0); \
        acc[1][1] = __builtin_amdgcn_mfma_f32_16x16x32_f16(_a1, CUR1, acc[1][1], 0, 0, 0); \
        acc[2][1] = __builtin_amdgcn_mfma_f32_16x16x32_f16(_a2, CUR1, acc[2][1], 0, 0, 0); \
        acc[3][1] = __builtin_amdgcn_mfma_f32_16x16x32_f16(_a3, CUR1, acc[3][1], 0, 0, 0); \
        acc[0][2] = __builtin_amdgcn_mfma_f32_16x16x32_f16(_a0, CUR2, acc[0][2], 0, 0, 0); \
        acc[1][2] = __builtin_amdgcn_mfma_f32_16x16x32_f16(_a1, CUR2, acc[1][2], 0, 0, 0); \
        acc[2][2] = __builtin_amdgcn_mfma_f32_16x16x32_f16(_a2, CUR2, acc[2][2], 0, 0, 0); \
        acc[3][2] = __builtin_amdgcn_mfma_f32_16x16x32_f16(_a3, CUR2, acc[3][2], 0, 0, 0); \
        acc[0][3] = __builtin_amdgcn_mfma_f32_16x16x32_f16(_a0, CUR3, acc[0][3], 0, 0, 0); \
        acc[1][3] = __builtin_amdgcn_mfma_f32_16x16x32_f16(_a1, CUR3, acc[1][3], 0, 0, 0); \
        acc[2][3] = __builtin_amdgcn_mfma_f32_16x16x32_f16(_a2, CUR3, acc[2][3], 0, 0, 0); \
        acc[3][3] = __builtin_amdgcn_mfma_f32_16x16x32_f16(_a3, CUR3, acc[3][3], 0, 0, 0); \
    }                                                                        \
    if (((T) & 15) == 15) EPI((T) >> 4);                                     \
} while (0)

// ---------------- kernel 2: f16 MFMA GEMM, A LDS-resident, B global->reg, no barriers --
// 512 blocks x 512 threads (8 waves 2x4, 1 block/CU at 128KB LDS).
// A slab (128 rows x 512 k f16) staged ONCE into LDS; B fragments loaded
// per-wave straight from global (wp is fragment-ordered; each step's 16KB
// tile is shared by all 8 waves -> L1-resident). Main loop has NO barriers:
// waves free-run; B double-buffered in named registers one step ahead.
__global__ __launch_bounds__(512, 1) void k_gemm(const char* __restrict__ xp,
                                                 const char* __restrict__ wp,
                                                 const float* __restrict__ wnorm,
                                                 int* __restrict__ idxo,
                                                 int* __restrict__ cand2o,
                                                 int* __restrict__ cand3o,
                                                 float* __restrict__ bestd) {
    __shared__ char smem[131072];   // A slab only
    const int tid = threadIdx.x;
    const int lane = tid & 63;
    const int wid = tid >> 6;                // 0..7
    const int wr = wid >> 2, wc = wid & 3;   // wave grid 2 x 4, wave tile 64x64
    const int rb = blockIdx.x;
    const char* xsrc = xp + (size_t)rb * 131072;

    f32x4 acc[4][4];
    #pragma unroll
    for (int i = 0; i < 4; ++i)
        #pragma unroll
        for (int j = 0; j < 4; ++j) acc[i][j] = (f32x4){0.f, 0.f, 0.f, 0.f};

    unsigned int k1[16], k2[16], k3[16];
    #pragma unroll
    for (int s = 0; s < 16; ++s) { k1[s] = k2[s] = k3[s] = 0xFFFFFFFFu; }

    // prologue: whole A slab once (xp layout == LDS layout, linear gll16 copy)
    #pragma unroll
    for (int i = 0; i < 16; ++i) {
        int c = wid * 16 + i;                // 128 chunks of 1024B
        gll16(xsrc + c * 1024 + lane * 16, smem + c * 1024);
    }
    // B(0) into registers (global, fragment-ordered)
    f16x8 b0_0, b0_1, b0_2, b0_3, b1_0, b1_1, b1_2, b1_3;
    {
        const char* n0 = wp + (size_t)(wc * 4) * 1024 + (size_t)lane * 16;
        b0_0 = *(const f16x8*)(n0);
        b0_1 = *(const f16x8*)(n0 + 1024);
        b0_2 = *(const f16x8*)(n0 + 2048);
        b0_3 = *(const f16x8*)(n0 + 3072);
    }
    __syncthreads();                         // A slab visible (drains vmcnt)

    // barrier-free main loop, B regs ping-pong (t=127 prefetches harmless OOB
    // into the ws scratch region; values never used)
    for (int t = 0; t < 128; t += 2) {
        GSTEP(t,     b0_0, b0_1, b0_2, b0_3, b1_0, b1_1, b1_2, b1_3);
        GSTEP(t + 1, b1_0, b1_1, b1_2, b1_3, b0_0, b0_1, b0_2, b0_3);
    }

    // butterfly top-3 merge across the 16 column-lanes of each slot
    #pragma unroll
    for (int s = 0; s < 16; ++s) {
        #pragma unroll
        for (int off = 1; off < 16; off <<= 1) {
            unsigned int b1 = (unsigned)__shfl_xor((int)k1[s], off, 16);
            unsigned int b2 = (unsigned)__shfl_xor((int)k2[s], off, 16);
            unsigned int b3 = (unsigned)__shfl_xor((int)k3[s], off, 16);
            MRG3(k1[s], k2[s], k3[s], b1, b2, b3);
        }
    }
    // lane (lane&15)==s owns slot s; static-unrolled select (rule #20)
    unsigned int m1 = 0, m2 = 0, m3 = 0;
    #pragma unroll
    for (int s = 0; s < 16; ++s) {
        bool mine = (lane & 15) == s;
        m1 = mine ? k1[s] : m1;
        m2 = mine ? k2[s] : m2;
        m3 = mine ? k3[s] : m3;
    }
    int sl = lane & 15;
    int rowl = wr * 64 + (sl >> 2) * 16 + (lane >> 4) * 4 + (sl & 3);
    __syncthreads();                         // MFMA loop fully done; reuse A region
    ((uint4*)smem)[rowl * 4 + wc] = make_uint4(m1, m2, m3, 0u);
    __syncthreads();
    if (tid < 128) {
        uint4 a = ((const uint4*)smem)[tid * 4 + 0];
        uint4 b = ((const uint4*)smem)[tid * 4 + 1];
        uint4 c = ((const uint4*)smem)[tid * 4 + 2];
        uint4 d = ((const uint4*)smem)[tid * 4 + 3];
        unsigned int K1 = a.x, K2 = a.y, K3 = a.z;
        MRG3(K1, K2, K3, b.x, b.y, b.z);
        MRG3(K1, K2, K3, c.x, c.y, c.z);
        MRG3(K1, K2, K3, d.x, d.y, d.z);
        float f1 = FDEC(K1);
        float f2 = FDEC(K2);
        float f3 = FDEC(K3);
        int row = rb * 128 + tid;
        idxo[row]   = (int)(K1 & 0x7FFu);
        bestd[row]  = f1;
        cand2o[row] = (f2 - f1 < MARGIN_P) ? (int)(K2 & 0x7FFu) : -1;
        cand3o[row] = (f3 - f1 < MARGIN_P) ? (int)(K3 & 0x7FFu) : -1;
    }
}

// ---------------- kernel 3: fused fp64 refine + gather + loss partial + histogram ----
__global__ __launch_bounds__(256) void k_gather2(const float* __restrict__ x,
                                                 const float* __restrict__ w,
                                                 const int* __restrict__ idxo,
                                                 const int* __restrict__ cand2o,
                                                 const int* __restrict__ cand3o,
                                                 const float* __restrict__ bestd,
                                                 const float* __restrict__ xnorm,
                                                 float* __restrict__ out,
                                                 int* __restrict__ hist,
                                                 double* __restrict__ part) {
    __shared__ double red[4];
    int wid = threadIdx.x >> 6, lane = threadIdx.x & 63;
    int n = blockIdx.x * 4 + wid;
    int c1 = idxo[n];
    int c2 = cand2o[n];
    int cfin = c1;
    double dist = (double)bestd[n];
    if (c2 >= 0) {
        int c3 = cand3o[n];
        int c3e = (c3 < 0) ? c1 : c3;
        const float* xr = x + (size_t)n * DIM;
        const float* w1 = w + (size_t)c1 * DIM;
        const float* w2 = w + (size_t)c2 * DIM;
        const float* w3 = w + (size_t)c3e * DIM;
        double s1 = 0.0, s2 = 0.0, s3 = 0.0;
        #pragma unroll
        for (int j = 0; j < DIM / 64; ++j) {
            int d = lane + 64 * j;
            double xv = (double)xr[d];
            double a = (double)w1[d], b = (double)w2[d], c = (double)w3[d];
            s1 += a * a - 2.0 * xv * a;
            s2 += b * b - 2.0 * xv * b;
            s3 += c * c - 2.0 * xv * c;
        }
        #pragma unroll
        for (int off = 32; off; off >>= 1) {
            s1 += __shfl_xor(s1, off, 64);
            s2 += __shfl_xor(s2, off, 64);
            s3 += __shfl_xor(s3, off, 64);
        }
        double bs = s1; int bi = c1;
        if (s2 < bs || (s2 == bs && c2 < bi)) { bs = s2; bi = c2; }
        if (c3 >= 0 && (s3 < bs || (s3 == bs && c3 < bi))) { bs = s3; bi = c3; }
        cfin = bi;
        dist = bs;
    }
    const float* wq = w + (size_t)cfin * DIM;
    float* oq = out + 1 + (size_t)n * DIM;   // quantized_st == quantized numerically
    #pragma unroll
    for (int j = 0; j < DIM / 64; ++j) {
        int d = j * 64 + lane;
        oq[d] = wq[d];
    }
    if (lane == 0) {
        red[wid] = dist + (double)xnorm[n];  // ||x-w||^2 = (||w||^2-2xw) + ||x||^2
        atomicAdd(&hist[cfin], 1);
        out[2 + NDTOT + n] = (float)cfin;
    }
    __syncthreads();
    if (threadIdx.x == 0)
        part[blockIdx.x] = red[0] + red[1] + red[2] + red[3];
}

// ---------------- kernel 4: deterministic finalize (loss + perplexity) ----------------
__global__ __launch_bounds__(256) void k_final2(const double* __restrict__ part,
                                                const int* __restrict__ hist,
                                                float* __restrict__ out) {
    __shared__ double sm[256];
    int t = threadIdx.x;
    double s = 0.0;
    for (int i = t; i < NROWS / 4; i += 256) s += part[i];
    sm[t] = s; __syncthreads();
    for (int off = 128; off; off >>= 1) { if (t < off) sm[t] += sm[t + off]; __syncthreads(); }
    if (t == 0) out[0] = (float)(sm[0] * 0.25 / (double)NDTOT);
    __syncthreads();
    double e = 0.0;
    for (int k = t; k < KCODES; k += 256) {
        double p = (double)hist[k] / (double)NROWS;
        e -= p * log(p + 1e-10);
    }
    sm[t] = e; __syncthreads();
    for (int off = 128; off; off >>= 1) { if (t < off) sm[t] += sm[t + off]; __syncthreads(); }
    if (t == 0) out[1 + NDTOT] = (float)exp(sm[0]);
}

extern "C" void kernel_launch(void* const* d_in, const int* in_sizes, int n_in,
                              void* d_out, int out_size, void* d_ws, size_t ws_size,
                              hipStream_t stream) {
    const float* x = (const float*)d_in[0];   // [64,1024,512] fp32
    const float* w = (const float*)d_in[1];   // [2048,512] fp32
    float* out = (float*)d_out;
    char* ws = (char*)d_ws;

    // xp (64 MB f16 fragment-ordered) lives in the d_out quantized region:
    // k_gemm consumes it before k_gather2 overwrites every byte with outputs.
    char* xp = (char*)d_out + 16;

    char*   wp    = ws;                            // 2 MB (+16KB OOB prefetch pad below)
    float*  wnorm = (float*)(ws + 2113536);        // 8 KB  (2MB + 16KB pad)
    int*    idxo  = (int*)(ws + 2121728);          // 256 KB
    int*    cand2 = (int*)(ws + 2383872);          // 256 KB
    int*    cand3 = (int*)(ws + 2646016);          // 256 KB
    int*    hist  = (int*)(ws + 2908160);          // 8 KB
    float*  xnorm = (float*)(ws + 2916352);        // 256 KB
    float*  bestd = (float*)(ws + 3178496);        // 256 KB
    double* part  = (double*)(ws + 3440640);       // 128 KB

    hipMemsetAsync(hist, 0, KCODES * sizeof(int), stream);
    k_prepw  <<<(KCODES * 64) / 256, 256, 0, stream>>>(w, wp, wnorm);
    k_prep   <<<(NROWS * 64) / 256, 256, 0, stream>>>(x, xp, xnorm);
    k_gemm   <<<NROWS / 128, 512, 0, stream>>>(xp, wp, wnorm, idxo, cand2, cand3, bestd);
    k_gather2<<<NROWS / 4, 256, 0, stream>>>(x, w, idxo, cand2, cand3, bestd, xnorm, out, hist, part);
    k_final2 <<<1, 256, 0, stream>>>(part, hist, out);
}

// Round 12
// 236.789 us; speedup vs baseline: 1.2171x; 1.2047x over previous
//
#include <hip/hip_runtime.h>
#include <hip/hip_fp16.h>
#include <cmath>

#define NROWS  65536
#define DIM    512
#define KCODES 2048
#define NDTOT  33554432LL   // NROWS*DIM
// refine trigger: f16-product error (14*sigma = 0.0625) + key truncation (0.001)
#define MARGIN_P 0.0635f

typedef __attribute__((ext_vector_type(8))) _Float16 f16x8;  // 8 f16 = 1 MFMA operand
typedef __attribute__((ext_vector_type(4))) float f32x4;

// branchless sorted-top3 insert of packed key v (u32 min/max keep regs, no addresses)
#define KINS3(K1,K2,K3,V) do {                       \
    unsigned int _v = (V);                           \
    unsigned int _h1 = max((K1), _v); (K1) = min((K1), _v); \
    unsigned int _h2 = max((K2), _h1); (K2) = min((K2), _h1); \
    (K3) = min((K3), _h2);                           \
} while (0)

// in-place merge of two sorted triples (A <- merge(A,B)), packed-key order
#define MRG3(A1,A2,A3,B1,B2,B3) do {                               \
    unsigned int _x1 = min((A1),(B1)), _y1 = max((A1),(B1));       \
    unsigned int _x2 = min((A2),(B2)), _y2 = max((A2),(B2));       \
    unsigned int _x3 = min((A3),(B3));                             \
    (A1) = _x1; (A2) = min(_y1,_x2);                               \
    (A3) = min(max(_y1,_x2), min(_x3,_y2));                        \
} while (0)

// key pack: dist+1024 in [1024,2048) -> exponent constant -> keep mantissa[22:2]
// in key[31:11], col in key[10:0]. umin order == (dist, col) lex order.
#define FDEC(K) (__uint_as_float(0x44800000u | ((((K) >> 11) & 0x1FFFFFu) << 2)) - 1024.f)

// ---------------- kernel 1: w -> f16 B-tile order + norms ----------------
// tile (cb 8 of 256 cols, ks32 16): 16384 B = [fcol 16][lane 64][16B];
// lane = ((k%32)/8)*16 + col%16, fcol = (col%256)/16.
__global__ __launch_bounds__(256) void k_prepw(const float* __restrict__ src,
                                               char* __restrict__ dst,
                                               float* __restrict__ norms) {
    long gid = (long)blockIdx.x * 256 + threadIdx.x;
    int c  = (int)(gid >> 6);
    int k8 = (int)(gid & 63);
    const float4* s = (const float4*)(src + (size_t)c * DIM + k8 * 8);
    float4 v0 = s[0], v1 = s[1];
    float vv[8] = {v0.x, v0.y, v0.z, v0.w, v1.x, v1.y, v1.z, v1.w};
    unsigned int hw[4];
    float nrm = 0.f;
    #pragma unroll
    for (int j = 0; j < 4; ++j) {
        unsigned int h0 = __half_as_ushort(__float2half_rn(vv[2*j]));
        unsigned int h1 = __half_as_ushort(__float2half_rn(vv[2*j+1]));
        hw[j] = h0 | (h1 << 16);
        nrm = fmaf(vv[2*j], vv[2*j], nrm);
        nrm = fmaf(vv[2*j+1], vv[2*j+1], nrm);
    }
    int cb = c >> 8, fcol = (c >> 4) & 15;
    int ks32 = k8 >> 2, sub = k8 & 3;
    int l = sub * 16 + (c & 15);
    size_t off = (size_t)((cb * 16 + ks32) * 16 + fcol) * 1024 + (size_t)l * 16;
    *(uint4*)(dst + off) = make_uint4(hw[0], hw[1], hw[2], hw[3]);
    #pragma unroll
    for (int o = 32; o; o >>= 1) nrm += __shfl_xor(nrm, o, 64);
    if ((threadIdx.x & 63) == 0) norms[c] = nrm;
}

// top-3 epilogue per 256-col block CB (acc consumed + reset)
#define EPI(CB) do {                                                         \
    _Pragma("unroll") for (int fc = 0; fc < 4; ++fc) {                       \
        unsigned int col = (unsigned)((CB) * 256 + wc * 64 + fc * 16 + (lane & 15)); \
        float wnb = wnorm[col] + 1024.f;                                     \
        _Pragma("unroll") for (int fr = 0; fr < 4; ++fr) {                   \
            _Pragma("unroll") for (int reg = 0; reg < 4; ++reg) {            \
                float kd = fmaf(-2.f, acc[fr][fc][reg], wnb);                \
                unsigned int key = ((__float_as_uint(kd) << 9) & 0xFFFFF800u) | col; \
                int s = fr * 4 + reg;                                        \
                KINS3(k1[s], k2[s], k3[s], key);                             \
            }                                                                \
            acc[fr][fc] = (f32x4){0.f, 0.f, 0.f, 0.f};                       \
        }                                                                    \
    }                                                                        \
} while (0)

// one barrier-free step: prefetch B(T+1) global->NXT regs, ds_read A (row-major
// XOR-swizzled), 16 MFMA with CUR regs, top-3 epilogue per 256-col block.
#define GSTEP(T, CUR0, CUR1, CUR2, CUR3, NXT0, NXT1, NXT2, NXT3) do {        \
    {                                                                        \
        const char* _n = wp + ((size_t)((T) + 1) << 14) + (size_t)(wc * 4) * 1024 + (size_t)lane * 16; \
        NXT0 = *(const f16x8*)(_n);                                          \
        NXT1 = *(const f16x8*)(_n + 1024);                                   \
        NXT2 = *(const f16x8*)(_n + 2048);                                   \
        NXT3 = *(const f16x8*)(_n + 3072);                                   \
    }                                                                        \
    {                                                                        \
        int _ks = (T) & 15;                                                  \
        unsigned _ab = (unsigned)((wr * 64 + (lane & 15)) * 1024 + _ks * 64  \
                                  + ((lane >> 4) << 4));                     \
        _ab ^= (unsigned)((lane & 7) << 4);                                  \
        const char* _a = smem + _ab;                                         \
        f16x8 _a0 = *(const f16x8*)(_a);                                     \
        f16x8 _a1 = *(const f16x8*)(_a + 16384);                             \
        f16x8 _a2 = *(const f16x8*)(_a + 32768);                             \
        f16x8 _a3 = *(const f16x8*)(_a + 49152);                             \
        acc[0][0] = __builtin_amdgcn_mfma_f32_16x16x32_f16(_a0, CUR0, acc[0][0], 0, 0, 0); \
        acc[1][0] = __builtin_amdgcn_mfma_f32_16x16x32_f16(_a1, CUR0, acc[1][0], 0, 0, 0); \
        acc[2][0] = __builtin_amdgcn_mfma_f32_16x16x32_f16(_a2, CUR0, acc[2][0], 0, 0, 0); \
        acc[3][0] = __builtin_amdgcn_mfma_f32_16x16x32_f16(_a3, CUR0, acc[3][0], 0, 0, 0); \
        acc[0][1] = __builtin_amdgcn_mfma_f32_16x16x32_f16(_a0, CUR1, acc[0][1], 0, 0, 0); \
        acc[1][1] = __builtin_amdgcn_mfma_f32_16x16x32_f16(_a1, CUR1, acc[1][1], 0, 0, 0); \
        acc[2][1] = __builtin_amdgcn_mfma_f32_16x16x32_f16(_a2, CUR1, acc[2][1], 0, 0, 0); \
        acc[3][1] = __builtin_amdgcn_mfma_f32_16x16x32_f16(_a3, CUR1, acc[3][1], 0, 0, 0); \
        acc[0][2] = __builtin_amdgcn_mfma_f32_16x16x32_f16(_a0, CUR2, acc[0][2], 0, 0, 0); \
        acc[1][2] = __builtin_amdgcn_mfma_f32_16x16x32_f16(_a1, CUR2, acc[1][2], 0, 0, 0); \
        acc[2][2] = __builtin_amdgcn_mfma_f32_16x16x32_f16(_a2, CUR2, acc[2][2], 0, 0, 0); \
        acc[3][2] = __builtin_amdgcn_mfma_f32_16x16x32_f16(_a3, CUR2, acc[3][2], 0, 0, 0); \
        acc[0][3] = __builtin_amdgcn_mfma_f32_16x16x32_f16(_a0, CUR3, acc[0][3], 0, 0, 0); \
        acc[1][3] = __builtin_amdgcn_mfma_f32_16x16x32_f16(_a1, CUR3, acc[1][3], 0, 0, 0); \
        acc[2][3] = __builtin_amdgcn_mfma_f32_16x16x32_f16(_a2, CUR3, acc[2][3], 0, 0, 0); \
        acc[3][3] = __builtin_amdgcn_mfma_f32_16x16x32_f16(_a3, CUR3, acc[3][3], 0, 0, 0); \
    }                                                                        \
    if (((T) & 15) == 15) EPI((T) >> 4);                                     \
} while (0)

// ---------------- kernel 2: fused x-convert + f16 MFMA GEMM + packed top-3 ----------
// 512 blocks x 512 threads (8 waves 2x4, 1 block/CU at 128KB LDS).
// Prologue: read own 256KB fp32 x slab (coalesced), convert to f16, write
// row-major XOR-swizzled A into LDS (write linear per wave -> conflict-free;
// read granule distribution uniform -> conflict-free), compute xnorm.
// Main loop (barrier-free, as r11): B fragments global->reg double-buffered,
// A from LDS, 16 MFMA/step.
__global__ __launch_bounds__(512, 1) void k_gemm(const float* __restrict__ x,
                                                 const char* __restrict__ wp,
                                                 const float* __restrict__ wnorm,
                                                 float* __restrict__ xnorm,
                                                 int* __restrict__ idxo,
                                                 int* __restrict__ cand2o,
                                                 int* __restrict__ cand3o,
                                                 float* __restrict__ bestd) {
    __shared__ char smem[131072];   // A slab, row-major swizzled: row*1024 + k*2
    const int tid = threadIdx.x;
    const int lane = tid & 63;
    const int wid = tid >> 6;                // 0..7
    const int wr = wid >> 2, wc = wid & 3;   // wave grid 2 x 4, wave tile 64x64
    const int rb = blockIdx.x;

    f32x4 acc[4][4];
    #pragma unroll
    for (int i = 0; i < 4; ++i)
        #pragma unroll
        for (int j = 0; j < 4; ++j) acc[i][j] = (f32x4){0.f, 0.f, 0.f, 0.f};

    unsigned int k1[16], k2[16], k3[16];
    #pragma unroll
    for (int s = 0; s < 16; ++s) { k1[s] = k2[s] = k3[s] = 0xFFFFFFFFu; }

    // ---- prologue: convert x fp32 -> f16 swizzled LDS + row norms ----
    const float* xs = x + (size_t)rb * 128 * DIM;
    #pragma unroll
    for (int pass = 0; pass < 16; ++pass) {
        int row = pass * 8 + wid;            // one row per wave per pass
        const float4* src = (const float4*)(xs + (size_t)row * DIM) + lane * 2;
        float4 u0 = src[0], u1 = src[1];
        unsigned int p0 = (unsigned int)__half_as_ushort(__float2half_rn(u0.x))
                        | ((unsigned int)__half_as_ushort(__float2half_rn(u0.y)) << 16);
        unsigned int p1 = (unsigned int)__half_as_ushort(__float2half_rn(u0.z))
                        | ((unsigned int)__half_as_ushort(__float2half_rn(u0.w)) << 16);
        unsigned int p2 = (unsigned int)__half_as_ushort(__float2half_rn(u1.x))
                        | ((unsigned int)__half_as_ushort(__float2half_rn(u1.y)) << 16);
        unsigned int p3 = (unsigned int)__half_as_ushort(__float2half_rn(u1.z))
                        | ((unsigned int)__half_as_ushort(__float2half_rn(u1.w)) << 16);
        unsigned int addr = (unsigned int)(row * 1024 + lane * 16);
        addr ^= (unsigned int)((row & 7) << 4);
        *(uint4*)(smem + addr) = make_uint4(p0, p1, p2, p3);
        float nr = u0.x * u0.x;
        nr = fmaf(u0.y, u0.y, nr); nr = fmaf(u0.z, u0.z, nr); nr = fmaf(u0.w, u0.w, nr);
        nr = fmaf(u1.x, u1.x, nr); nr = fmaf(u1.y, u1.y, nr);
        nr = fmaf(u1.z, u1.z, nr); nr = fmaf(u1.w, u1.w, nr);
        #pragma unroll
        for (int o = 32; o; o >>= 1) nr += __shfl_xor(nr, o, 64);
        if (lane == 0) xnorm[rb * 128 + row] = nr;
    }
    // B(0) into registers (global, fragment-ordered)
    f16x8 b0_0, b0_1, b0_2, b0_3, b1_0, b1_1, b1_2, b1_3;
    {
        const char* n0 = wp + (size_t)(wc * 4) * 1024 + (size_t)lane * 16;
        b0_0 = *(const f16x8*)(n0);
        b0_1 = *(const f16x8*)(n0 + 1024);
        b0_2 = *(const f16x8*)(n0 + 2048);
        b0_3 = *(const f16x8*)(n0 + 3072);
    }
    __syncthreads();                         // A slab visible to all waves

    // barrier-free main loop, B regs ping-pong (t=127 prefetches harmless OOB
    // into the padded wp region; values never used)
    for (int t = 0; t < 128; t += 2) {
        GSTEP(t,     b0_0, b0_1, b0_2, b0_3, b1_0, b1_1, b1_2, b1_3);
        GSTEP(t + 1, b1_0, b1_1, b1_2, b1_3, b0_0, b0_1, b0_2, b0_3);
    }

    // butterfly top-3 merge across the 16 column-lanes of each slot
    #pragma unroll
    for (int s = 0; s < 16; ++s) {
        #pragma unroll
        for (int off = 1; off < 16; off <<= 1) {
            unsigned int b1 = (unsigned)__shfl_xor((int)k1[s], off, 16);
            unsigned int b2 = (unsigned)__shfl_xor((int)k2[s], off, 16);
            unsigned int b3 = (unsigned)__shfl_xor((int)k3[s], off, 16);
            MRG3(k1[s], k2[s], k3[s], b1, b2, b3);
        }
    }
    // lane (lane&15)==s owns slot s; static-unrolled select (rule #20)
    unsigned int m1 = 0, m2 = 0, m3 = 0;
    #pragma unroll
    for (int s = 0; s < 16; ++s) {
        bool mine = (lane & 15) == s;
        m1 = mine ? k1[s] : m1;
        m2 = mine ? k2[s] : m2;
        m3 = mine ? k3[s] : m3;
    }
    int sl = lane & 15;
    int rowl = wr * 64 + (sl >> 2) * 16 + (lane >> 4) * 4 + (sl & 3);
    __syncthreads();                         // MFMA loop fully done; reuse A region
    ((uint4*)smem)[rowl * 4 + wc] = make_uint4(m1, m2, m3, 0u);
    __syncthreads();
    if (tid < 128) {
        uint4 a = ((const uint4*)smem)[tid * 4 + 0];
        uint4 b = ((const uint4*)smem)[tid * 4 + 1];
        uint4 c = ((const uint4*)smem)[tid * 4 + 2];
        uint4 d = ((const uint4*)smem)[tid * 4 + 3];
        unsigned int K1 = a.x, K2 = a.y, K3 = a.z;
        MRG3(K1, K2, K3, b.x, b.y, b.z);
        MRG3(K1, K2, K3, c.x, c.y, c.z);
        MRG3(K1, K2, K3, d.x, d.y, d.z);
        float f1 = FDEC(K1);
        float f2 = FDEC(K2);
        float f3 = FDEC(K3);
        int row = rb * 128 + tid;
        idxo[row]   = (int)(K1 & 0x7FFu);
        bestd[row]  = f1;
        cand2o[row] = (f2 - f1 < MARGIN_P) ? (int)(K2 & 0x7FFu) : -1;
        cand3o[row] = (f3 - f1 < MARGIN_P) ? (int)(K3 & 0x7FFu) : -1;
    }
}

// ---------------- kernel 3: fused fp64 refine + gather + loss partial + histogram ----
__global__ __launch_bounds__(256) void k_gather2(const float* __restrict__ x,
                                                 const float* __restrict__ w,
                                                 const int* __restrict__ idxo,
                                                 const int* __restrict__ cand2o,
                                                 const int* __restrict__ cand3o,
                                                 const float* __restrict__ bestd,
                                                 const float* __restrict__ xnorm,
                                                 float* __restrict__ out,
                                                 int* __restrict__ hist,
                                                 double* __restrict__ part) {
    __shared__ double red[4];
    int wid = threadIdx.x >> 6, lane = threadIdx.x & 63;
    int n = blockIdx.x * 4 + wid;
    int c1 = idxo[n];
    int c2 = cand2o[n];
    int cfin = c1;
    double dist = (double)bestd[n];
    if (c2 >= 0) {
        int c3 = cand3o[n];
        int c3e = (c3 < 0) ? c1 : c3;
        const float* xr = x + (size_t)n * DIM;
        const float* w1 = w + (size_t)c1 * DIM;
        const float* w2 = w + (size_t)c2 * DIM;
        const float* w3 = w + (size_t)c3e * DIM;
        double s1 = 0.0, s2 = 0.0, s3 = 0.0;
        #pragma unroll
        for (int j = 0; j < DIM / 64; ++j) {
            int d = lane + 64 * j;
            double xv = (double)xr[d];
            double a = (double)w1[d], b = (double)w2[d], c = (double)w3[d];
            s1 += a * a - 2.0 * xv * a;
            s2 += b * b - 2.0 * xv * b;
            s3 += c * c - 2.0 * xv * c;
        }
        #pragma unroll
        for (int off = 32; off; off >>= 1) {
            s1 += __shfl_xor(s1, off, 64);
            s2 += __shfl_xor(s2, off, 64);
            s3 += __shfl_xor(s3, off, 64);
        }
        double bs = s1; int bi = c1;
        if (s2 < bs || (s2 == bs && c2 < bi)) { bs = s2; bi = c2; }
        if (c3 >= 0 && (s3 < bs || (s3 == bs && c3 < bi))) { bs = s3; bi = c3; }
        cfin = bi;
        dist = bs;
    }
    const float* wq = w + (size_t)cfin * DIM;
    float* oq = out + 1 + (size_t)n * DIM;   // quantized_st == quantized numerically
    #pragma unroll
    for (int j = 0; j < DIM / 64; ++j) {
        int d = j * 64 + lane;
        oq[d] = wq[d];
    }
    if (lane == 0) {
        red[wid] = dist + (double)xnorm[n];  // ||x-w||^2 = (||w||^2-2xw) + ||x||^2
        atomicAdd(&hist[cfin], 1);
        out[2 + NDTOT + n] = (float)cfin;
    }
    __syncthreads();
    if (threadIdx.x == 0)
        part[blockIdx.x] = red[0] + red[1] + red[2] + red[3];
}

// ---------------- kernel 4: deterministic finalize (loss + perplexity) ----------------
__global__ __launch_bounds__(256) void k_final2(const double* __restrict__ part,
                                                const int* __restrict__ hist,
                                                float* __restrict__ out) {
    __shared__ double sm[256];
    int t = threadIdx.x;
    double s = 0.0;
    for (int i = t; i < NROWS / 4; i += 256) s += part[i];
    sm[t] = s; __syncthreads();
    for (int off = 128; off; off >>= 1) { if (t < off) sm[t] += sm[t + off]; __syncthreads(); }
    if (t == 0) out[0] = (float)(sm[0] * 0.25 / (double)NDTOT);
    __syncthreads();
    double e = 0.0;
    for (int k = t; k < KCODES; k += 256) {
        double p = (double)hist[k] / (double)NROWS;
        e -= p * log(p + 1e-10);
    }
    sm[t] = e; __syncthreads();
    for (int off = 128; off; off >>= 1) { if (t < off) sm[t] += sm[t + off]; __syncthreads(); }
    if (t == 0) out[1 + NDTOT] = (float)exp(sm[0]);
}

extern "C" void kernel_launch(void* const* d_in, const int* in_sizes, int n_in,
                              void* d_out, int out_size, void* d_ws, size_t ws_size,
                              hipStream_t stream) {
    const float* x = (const float*)d_in[0];   // [64,1024,512] fp32
    const float* w = (const float*)d_in[1];   // [2048,512] fp32
    float* out = (float*)d_out;
    char* ws = (char*)d_ws;

    char*   wp    = ws;                            // 2 MB (+16KB OOB prefetch pad)
    float*  wnorm = (float*)(ws + 2113536);        // 8 KB  (2MB + 16KB pad)
    int*    idxo  = (int*)(ws + 2121728);          // 256 KB
    int*    cand2 = (int*)(ws + 2383872);          // 256 KB
    int*    cand3 = (int*)(ws + 2646016);          // 256 KB
    int*    hist  = (int*)(ws + 2908160);          // 8 KB
    float*  xnorm = (float*)(ws + 2916352);        // 256 KB
    float*  bestd = (float*)(ws + 3178496);        // 256 KB
    double* part  = (double*)(ws + 3440640);       // 128 KB

    hipMemsetAsync(hist, 0, KCODES * sizeof(int), stream);
    k_prepw  <<<(KCODES * 64) / 256, 256, 0, stream>>>(w, wp, wnorm);
    k_gemm   <<<NROWS / 128, 512, 0, stream>>>(x, wp, wnorm, xnorm, idxo, cand2, cand3, bestd);
    k_gather2<<<NROWS / 4, 256, 0, stream>>>(x, w, idxo, cand2, cand3, bestd, xnorm, out, hist, part);
    k_final2 <<<1, 256, 0, stream>>>(part, hist, out);
}

// Round 13
// 223.112 us; speedup vs baseline: 1.2917x; 1.0613x over previous
//
#include <hip/hip_runtime.h>
#include <hip/hip_fp16.h>
#include <cmath>

#define NROWS  65536
#define DIM    512
#define KCODES 2048
#define NDTOT  33554432LL   // NROWS*DIM
// refine trigger: f16-product error (14*sigma = 0.0625) + key truncation (0.001)
#define MARGIN_P 0.0635f

typedef __attribute__((ext_vector_type(8))) _Float16 f16x8;  // 8 f16 = 1 MFMA operand
typedef __attribute__((ext_vector_type(4))) float f32x4;

// branchless sorted-top3 insert of packed key v (u32 min/max keep regs, no addresses)
#define KINS3(K1,K2,K3,V) do {                       \
    unsigned int _v = (V);                           \
    unsigned int _h1 = max((K1), _v); (K1) = min((K1), _v); \
    unsigned int _h2 = max((K2), _h1); (K2) = min((K2), _h1); \
    (K3) = min((K3), _h2);                           \
} while (0)

// in-place merge of two sorted triples (A <- merge(A,B)), packed-key order
#define MRG3(A1,A2,A3,B1,B2,B3) do {                               \
    unsigned int _x1 = min((A1),(B1)), _y1 = max((A1),(B1));       \
    unsigned int _x2 = min((A2),(B2)), _y2 = max((A2),(B2));       \
    unsigned int _x3 = min((A3),(B3));                             \
    (A1) = _x1; (A2) = min(_y1,_x2);                               \
    (A3) = min(max(_y1,_x2), min(_x3,_y2));                        \
} while (0)

// key pack: dist+1024 in [1024,2048) -> exponent constant -> keep mantissa[22:2]
// in key[31:11], col in key[10:0]. umin order == (dist, col) lex order.
#define FDEC(K) (__uint_as_float(0x44800000u | ((((K) >> 11) & 0x1FFFFFu) << 2)) - 1024.f)

// ---------------- kernel 1: w -> f16 B-tile order + norms ----------------
// tile (cb 8 of 256 cols, ks32 16): 16384 B = [fcol 16][lane 64][16B];
// lane = ((k%32)/8)*16 + col%16, fcol = (col%256)/16.
__global__ __launch_bounds__(256) void k_prepw(const float* __restrict__ src,
                                               char* __restrict__ dst,
                                               float* __restrict__ norms) {
    long gid = (long)blockIdx.x * 256 + threadIdx.x;
    int c  = (int)(gid >> 6);
    int k8 = (int)(gid & 63);
    const float4* s = (const float4*)(src + (size_t)c * DIM + k8 * 8);
    float4 v0 = s[0], v1 = s[1];
    float vv[8] = {v0.x, v0.y, v0.z, v0.w, v1.x, v1.y, v1.z, v1.w};
    unsigned int hw[4];
    float nrm = 0.f;
    #pragma unroll
    for (int j = 0; j < 4; ++j) {
        unsigned int h0 = __half_as_ushort(__float2half_rn(vv[2*j]));
        unsigned int h1 = __half_as_ushort(__float2half_rn(vv[2*j+1]));
        hw[j] = h0 | (h1 << 16);
        nrm = fmaf(vv[2*j], vv[2*j], nrm);
        nrm = fmaf(vv[2*j+1], vv[2*j+1], nrm);
    }
    int cb = c >> 8, fcol = (c >> 4) & 15;
    int ks32 = k8 >> 2, sub = k8 & 3;
    int l = sub * 16 + (c & 15);
    size_t off = (size_t)((cb * 16 + ks32) * 16 + fcol) * 1024 + (size_t)l * 16;
    *(uint4*)(dst + off) = make_uint4(hw[0], hw[1], hw[2], hw[3]);
    #pragma unroll
    for (int o = 32; o; o >>= 1) nrm += __shfl_xor(nrm, o, 64);
    if ((threadIdx.x & 63) == 0) norms[c] = nrm;
}

// ---------------- kernel 2: fused x-convert + f16 MFMA GEMM + packed top-3 ----------
// 512 blocks x 1024 threads (16 waves, grid 2x8, wave tile 64x32, 4 waves/SIMD).
// A slab in FRAGMENT order (r7-r11 proven conflict-free: lane*16 contiguous),
// converted in-kernel: wave wid owns dims [wid*32,wid*32+32) = chunk
// (ks64=wid>>1, ksub=wid&1); per frow, lane l converts row frow*16+(l&15),
// k-sub (l>>4)*8 and writes LDS offset l*16 (contiguous 1KB -> conflict-free).
// Main loop barrier-free: A read-only in LDS; B fragments global->reg (L1-hit,
// tile shared by all 16 waves); 8 MFMA/step/wave; TLP (4 waves/SIMD) hides
// latency instead of software pipelining.
__global__ __launch_bounds__(1024, 1) void k_gemm(const float* __restrict__ x,
                                                  const char* __restrict__ wp,
                                                  const float* __restrict__ wnorm,
                                                  float* __restrict__ xnorm,
                                                  int* __restrict__ idxo,
                                                  int* __restrict__ cand2o,
                                                  int* __restrict__ cand3o,
                                                  float* __restrict__ bestd) {
    __shared__ char smem[139776];   // A frag-order 131072 + xnorm partials 128*17*4
    const int tid = threadIdx.x;
    const int lane = tid & 63;
    const int wid = tid >> 6;                // 0..15
    const int wr = wid >> 3, wc = wid & 7;   // wave grid 2 x 8, wave tile 64x32
    const int rb = blockIdx.x;
    float* pn = (float*)(smem + 131072);     // [128][17] xnorm partials (padded)

    f32x4 acc[4][2];
    #pragma unroll
    for (int i = 0; i < 4; ++i)
        #pragma unroll
        for (int j = 0; j < 2; ++j) acc[i][j] = (f32x4){0.f, 0.f, 0.f, 0.f};

    unsigned int k1[16], k2[16], k3[16];
    #pragma unroll
    for (int s = 0; s < 16; ++s) { k1[s] = k2[s] = k3[s] = 0xFFFFFFFFu; }

    // ---- prologue: fp32 -> f16 fragment-order LDS + xnorm partials ----
    const float* xs = x + (size_t)rb * 128 * DIM;
    const unsigned chunkbase = (unsigned)((wid >> 1) * 16384 + (wid & 1) * 8192);
    #pragma unroll
    for (int frow = 0; frow < 8; ++frow) {
        int row = frow * 16 + (lane & 15);
        const float* src = xs + (size_t)row * DIM + wid * 32 + (lane >> 4) * 8;
        float4 u0 = *(const float4*)(src);
        float4 u1 = *(const float4*)(src + 4);
        unsigned int p0 = (unsigned int)__half_as_ushort(__float2half_rn(u0.x))
                        | ((unsigned int)__half_as_ushort(__float2half_rn(u0.y)) << 16);
        unsigned int p1 = (unsigned int)__half_as_ushort(__float2half_rn(u0.z))
                        | ((unsigned int)__half_as_ushort(__float2half_rn(u0.w)) << 16);
        unsigned int p2 = (unsigned int)__half_as_ushort(__float2half_rn(u1.x))
                        | ((unsigned int)__half_as_ushort(__float2half_rn(u1.y)) << 16);
        unsigned int p3 = (unsigned int)__half_as_ushort(__float2half_rn(u1.z))
                        | ((unsigned int)__half_as_ushort(__float2half_rn(u1.w)) << 16);
        *(uint4*)(smem + chunkbase + frow * 1024 + lane * 16) = make_uint4(p0, p1, p2, p3);
        float nr = u0.x * u0.x;
        nr = fmaf(u0.y, u0.y, nr); nr = fmaf(u0.z, u0.z, nr); nr = fmaf(u0.w, u0.w, nr);
        nr = fmaf(u1.x, u1.x, nr); nr = fmaf(u1.y, u1.y, nr);
        nr = fmaf(u1.z, u1.z, nr); nr = fmaf(u1.w, u1.w, nr);
        nr += __shfl_xor(nr, 16, 64);
        nr += __shfl_xor(nr, 32, 64);        // lanes 0-15: row partial over 32 dims
        if (lane < 16) pn[row * 17 + wid] = nr;
    }
    __syncthreads();                         // A slab + partials visible
    if (tid < 128) {
        float s = 0.f;
        #pragma unroll
        for (int j = 0; j < 16; ++j) s += pn[tid * 17 + j];
        xnorm[rb * 128 + tid] = s;
    }

    // ---- barrier-free main loop: cb outer (8 x 256 cols), ks inner (16 x K=32) ----
    for (int cb = 0; cb < 8; ++cb) {
        #pragma unroll 4
        for (int ks = 0; ks < 16; ++ks) {
            int t = cb * 16 + ks;
            const char* bp = wp + ((size_t)t << 14) + (size_t)(wc * 2) * 1024
                           + (size_t)lane * 16;
            f16x8 b0 = *(const f16x8*)(bp);
            f16x8 b1 = *(const f16x8*)(bp + 1024);
            const char* a = smem + (ks >> 1) * 16384 + (ks & 1) * 8192
                          + (wr * 4) * 1024 + lane * 16;
            f16x8 a0 = *(const f16x8*)(a);
            f16x8 a1 = *(const f16x8*)(a + 1024);
            f16x8 a2 = *(const f16x8*)(a + 2048);
            f16x8 a3 = *(const f16x8*)(a + 3072);
            acc[0][0] = __builtin_amdgcn_mfma_f32_16x16x32_f16(a0, b0, acc[0][0], 0, 0, 0);
            acc[1][0] = __builtin_amdgcn_mfma_f32_16x16x32_f16(a1, b0, acc[1][0], 0, 0, 0);
            acc[2][0] = __builtin_amdgcn_mfma_f32_16x16x32_f16(a2, b0, acc[2][0], 0, 0, 0);
            acc[3][0] = __builtin_amdgcn_mfma_f32_16x16x32_f16(a3, b0, acc[3][0], 0, 0, 0);
            acc[0][1] = __builtin_amdgcn_mfma_f32_16x16x32_f16(a0, b1, acc[0][1], 0, 0, 0);
            acc[1][1] = __builtin_amdgcn_mfma_f32_16x16x32_f16(a1, b1, acc[1][1], 0, 0, 0);
            acc[2][1] = __builtin_amdgcn_mfma_f32_16x16x32_f16(a2, b1, acc[2][1], 0, 0, 0);
            acc[3][1] = __builtin_amdgcn_mfma_f32_16x16x32_f16(a3, b1, acc[3][1], 0, 0, 0);
        }
        // top-3 epilogue for this 256-col block
        #pragma unroll
        for (int fc = 0; fc < 2; ++fc) {
            unsigned int col = (unsigned)(cb * 256 + wc * 32 + fc * 16 + (lane & 15));
            float wnb = wnorm[col] + 1024.f;
            #pragma unroll
            for (int fr = 0; fr < 4; ++fr) {
                #pragma unroll
                for (int reg = 0; reg < 4; ++reg) {
                    float kd = fmaf(-2.f, acc[fr][fc][reg], wnb);
                    unsigned int key = ((__float_as_uint(kd) << 9) & 0xFFFFF800u) | col;
                    int s = fr * 4 + reg;
                    KINS3(k1[s], k2[s], k3[s], key);
                }
                acc[fr][fc] = (f32x4){0.f, 0.f, 0.f, 0.f};
            }
        }
    }

    // butterfly top-3 merge across the 16 column-lanes of each slot
    #pragma unroll
    for (int s = 0; s < 16; ++s) {
        #pragma unroll
        for (int off = 1; off < 16; off <<= 1) {
            unsigned int b1 = (unsigned)__shfl_xor((int)k1[s], off, 16);
            unsigned int b2 = (unsigned)__shfl_xor((int)k2[s], off, 16);
            unsigned int b3 = (unsigned)__shfl_xor((int)k3[s], off, 16);
            MRG3(k1[s], k2[s], k3[s], b1, b2, b3);
        }
    }
    // lane (lane&15)==s owns slot s; static-unrolled select (rule #20)
    unsigned int m1 = 0, m2 = 0, m3 = 0;
    #pragma unroll
    for (int s = 0; s < 16; ++s) {
        bool mine = (lane & 15) == s;
        m1 = mine ? k1[s] : m1;
        m2 = mine ? k2[s] : m2;
        m3 = mine ? k3[s] : m3;
    }
    int sl = lane & 15;
    int rowl = wr * 64 + (sl >> 2) * 16 + (lane >> 4) * 4 + (sl & 3);
    __syncthreads();                         // MFMA loop fully done; reuse A region
    ((uint4*)smem)[rowl * 8 + wc] = make_uint4(m1, m2, m3, 0u);
    __syncthreads();
    if (tid < 128) {
        const uint4* e = (const uint4*)smem + tid * 8;
        uint4 e0 = e[0];
        unsigned int K1 = e0.x, K2 = e0.y, K3 = e0.z;
        #pragma unroll
        for (int j = 1; j < 8; ++j) {
            uint4 ej = e[j];
            MRG3(K1, K2, K3, ej.x, ej.y, ej.z);
        }
        float f1 = FDEC(K1);
        float f2 = FDEC(K2);
        float f3 = FDEC(K3);
        int row = rb * 128 + tid;
        idxo[row]   = (int)(K1 & 0x7FFu);
        bestd[row]  = f1;
        cand2o[row] = (f2 - f1 < MARGIN_P) ? (int)(K2 & 0x7FFu) : -1;
        cand3o[row] = (f3 - f1 < MARGIN_P) ? (int)(K3 & 0x7FFu) : -1;
    }
}

// ---------------- kernel 3: fused fp64 refine + gather + loss partial + histogram ----
__global__ __launch_bounds__(256) void k_gather2(const float* __restrict__ x,
                                                 const float* __restrict__ w,
                                                 const int* __restrict__ idxo,
                                                 const int* __restrict__ cand2o,
                                                 const int* __restrict__ cand3o,
                                                 const float* __restrict__ bestd,
                                                 const float* __restrict__ xnorm,
                                                 float* __restrict__ out,
                                                 int* __restrict__ hist,
                                                 double* __restrict__ part) {
    __shared__ double red[4];
    int wid = threadIdx.x >> 6, lane = threadIdx.x & 63;
    int n = blockIdx.x * 4 + wid;
    int c1 = idxo[n];
    int c2 = cand2o[n];
    int cfin = c1;
    double dist = (double)bestd[n];
    if (c2 >= 0) {
        int c3 = cand3o[n];
        int c3e = (c3 < 0) ? c1 : c3;
        const float* xr = x + (size_t)n * DIM;
        const float* w1 = w + (size_t)c1 * DIM;
        const float* w2 = w + (size_t)c2 * DIM;
        const float* w3 = w + (size_t)c3e * DIM;
        double s1 = 0.0, s2 = 0.0, s3 = 0.0;
        #pragma unroll
        for (int j = 0; j < DIM / 64; ++j) {
            int d = lane + 64 * j;
            double xv = (double)xr[d];
            double a = (double)w1[d], b = (double)w2[d], c = (double)w3[d];
            s1 += a * a - 2.0 * xv * a;
            s2 += b * b - 2.0 * xv * b;
            s3 += c * c - 2.0 * xv * c;
        }
        #pragma unroll
        for (int off = 32; off; off >>= 1) {
            s1 += __shfl_xor(s1, off, 64);
            s2 += __shfl_xor(s2, off, 64);
            s3 += __shfl_xor(s3, off, 64);
        }
        double bs = s1; int bi = c1;
        if (s2 < bs || (s2 == bs && c2 < bi)) { bs = s2; bi = c2; }
        if (c3 >= 0 && (s3 < bs || (s3 == bs && c3 < bi))) { bs = s3; bi = c3; }
        cfin = bi;
        dist = bs;
    }
    const float* wq = w + (size_t)cfin * DIM;
    float* oq = out + 1 + (size_t)n * DIM;   // quantized_st == quantized numerically
    #pragma unroll
    for (int j = 0; j < DIM / 64; ++j) {
        int d = j * 64 + lane;
        oq[d] = wq[d];
    }
    if (lane == 0) {
        red[wid] = dist + (double)xnorm[n];  // ||x-w||^2 = (||w||^2-2xw) + ||x||^2
        atomicAdd(&hist[cfin], 1);
        out[2 + NDTOT + n] = (float)cfin;
    }
    __syncthreads();
    if (threadIdx.x == 0)
        part[blockIdx.x] = red[0] + red[1] + red[2] + red[3];
}

// ---------------- kernel 4: deterministic finalize (loss + perplexity) ----------------
__global__ __launch_bounds__(256) void k_final2(const double* __restrict__ part,
                                                const int* __restrict__ hist,
                                                float* __restrict__ out) {
    __shared__ double sm[256];
    int t = threadIdx.x;
    double s = 0.0;
    for (int i = t; i < NROWS / 4; i += 256) s += part[i];
    sm[t] = s; __syncthreads();
    for (int off = 128; off; off >>= 1) { if (t < off) sm[t] += sm[t + off]; __syncthreads(); }
    if (t == 0) out[0] = (float)(sm[0] * 0.25 / (double)NDTOT);
    __syncthreads();
    double e = 0.0;
    for (int k = t; k < KCODES; k += 256) {
        double p = (double)hist[k] / (double)NROWS;
        e -= p * log(p + 1e-10);
    }
    sm[t] = e; __syncthreads();
    for (int off = 128; off; off >>= 1) { if (t < off) sm[t] += sm[t + off]; __syncthreads(); }
    if (t == 0) out[1 + NDTOT] = (float)exp(sm[0]);
}

extern "C" void kernel_launch(void* const* d_in, const int* in_sizes, int n_in,
                              void* d_out, int out_size, void* d_ws, size_t ws_size,
                              hipStream_t stream) {
    const float* x = (const float*)d_in[0];   // [64,1024,512] fp32
    const float* w = (const float*)d_in[1];   // [2048,512] fp32
    float* out = (float*)d_out;
    char* ws = (char*)d_ws;

    char*   wp    = ws;                            // 2 MB (+16KB pad)
    float*  wnorm = (float*)(ws + 2113536);        // 8 KB
    int*    idxo  = (int*)(ws + 2121728);          // 256 KB
    int*    cand2 = (int*)(ws + 2383872);          // 256 KB
    int*    cand3 = (int*)(ws + 2646016);          // 256 KB
    int*    hist  = (int*)(ws + 2908160);          // 8 KB
    float*  xnorm = (float*)(ws + 2916352);        // 256 KB
    float*  bestd = (float*)(ws + 3178496);        // 256 KB
    double* part  = (double*)(ws + 3440640);       // 128 KB

    hipMemsetAsync(hist, 0, KCODES * sizeof(int), stream);
    k_prepw  <<<(KCODES * 64) / 256, 256, 0, stream>>>(w, wp, wnorm);
    k_gemm   <<<NROWS / 128, 1024, 0, stream>>>(x, wp, wnorm, xnorm, idxo, cand2, cand3, bestd);
    k_gather2<<<NROWS / 4, 256, 0, stream>>>(x, w, idxo, cand2, cand3, bestd, xnorm, out, hist, part);
    k_final2 <<<1, 256, 0, stream>>>(part, hist, out);
}